// Round 1
// baseline (398.301 us; speedup 1.0000x reference)
//
#include <hip/hip_runtime.h>
#include <stdint.h>

#define HID 1024
#define NH 16
#define HD 64
#define BATCH 2
#define SEQ 2048
#define MR (BATCH*SEQ)        // 4096 token rows
#define NQKV (3*HID)          // 3072

typedef __attribute__((ext_vector_type(8))) short s16x8;
typedef __attribute__((ext_vector_type(8))) unsigned short u16x8;
typedef __attribute__((ext_vector_type(4))) float f32x4;

static __device__ __forceinline__ unsigned short f2bf(float f) {
  union { float f; unsigned u; } v; v.f = f;
  unsigned r = v.u + 0x7fffu + ((v.u >> 16) & 1u);   // RN-even
  return (unsigned short)(r >> 16);
}
static __device__ __forceinline__ float bf2f(unsigned short u) {
  union { float f; unsigned u; } v; v.u = ((unsigned)u) << 16; return v.f;
}

// ---------------- kernel 1: split x (fp32 -> bf16 hi/lo planes) --------------
__global__ __launch_bounds__(256) void k_split_x(const float4* __restrict__ x4,
                                                 unsigned short* __restrict__ hi,
                                                 unsigned short* __restrict__ lo) {
  int i = blockIdx.x * 256 + threadIdx.x;      // one float4 per thread
  float4 v = x4[i];
  ushort4 h, l;
  h.x = f2bf(v.x); l.x = f2bf(v.x - bf2f(h.x));
  h.y = f2bf(v.y); l.y = f2bf(v.y - bf2f(h.y));
  h.z = f2bf(v.z); l.z = f2bf(v.z - bf2f(h.z));
  h.w = f2bf(v.w); l.w = f2bf(v.w - bf2f(h.w));
  *(ushort4*)(hi + 4 * (size_t)i) = h;
  *(ushort4*)(lo + 4 * (size_t)i) = l;
}

// -------- kernel 2: transpose fp32 [R][C] -> bf16 split [C][R] ---------------
__global__ __launch_bounds__(256) void k_transpose_split(const float* __restrict__ src,
                                                         int R, int C,
                                                         unsigned short* __restrict__ dhi,
                                                         unsigned short* __restrict__ dlo) {
  __shared__ float tile[32][33];
  int tx = threadIdx.x, ty = threadIdx.y;              // 32 x 8
  int col0 = blockIdx.x * 32, row0 = blockIdx.y * 32;
  #pragma unroll
  for (int i = 0; i < 32; i += 8)
    tile[ty + i][tx] = src[(size_t)(row0 + ty + i) * C + col0 + tx];
  __syncthreads();
  #pragma unroll
  for (int i = 0; i < 32; i += 8) {
    float v = tile[tx][ty + i];
    int orow = col0 + ty + i;      // dst row = src col
    int ocol = row0 + tx;          // dst col = src row
    unsigned short h = f2bf(v);
    dhi[(size_t)orow * R + ocol] = h;
    if (dlo) dlo[(size_t)orow * R + ocol] = f2bf(v - bf2f(h));
  }
}

// ---------------- kernel 3: QKV GEMM (split bf16x2, 3-term) ------------------
// C[m][n] = sum_k A[m][k]*Bt[n][k] + bias[n];  A=x (4096x1024), Bt=WqkvT (3072x1024)
// epilogue scatters to Q[bh][t][d], K[bh][t][d], Vt[bh][d][t] (bf16)
__global__ __launch_bounds__(256) void k_gemm_qkv(const unsigned short* __restrict__ Ahi,
                                                  const unsigned short* __restrict__ Alo,
                                                  const unsigned short* __restrict__ Bhi,
                                                  const unsigned short* __restrict__ Blo,
                                                  const float* __restrict__ bias,
                                                  unsigned short* __restrict__ Qp,
                                                  unsigned short* __restrict__ Kp,
                                                  unsigned short* __restrict__ Vt) {
  const int K = HID;
  int tid = threadIdx.x;
  int wave = tid >> 6, lane = tid & 63, quad = lane >> 4, l16 = lane & 15;
  int wm = wave >> 1, wn = wave & 1;
  int m0 = blockIdx.y * 128, n0 = blockIdx.x * 128;
  __shared__ __align__(16) unsigned short As_h[128 * 32], As_l[128 * 32];
  __shared__ __align__(16) unsigned short Bs_h[128 * 32], Bs_l[128 * 32];
  f32x4 acc[4][4] = {};
  for (int k0 = 0; k0 < K; k0 += 32) {
    __syncthreads();
    for (int c = tid; c < 512; c += 256) {          // 512 chunks of 8 bf16
      int r = c >> 2, co = (c & 3) << 3;
      size_t ga = (size_t)(m0 + r) * K + k0 + co;
      *(u16x8*)&As_h[c << 3] = *(const u16x8*)&Ahi[ga];
      *(u16x8*)&As_l[c << 3] = *(const u16x8*)&Alo[ga];
      size_t gb = (size_t)(n0 + r) * K + k0 + co;
      *(u16x8*)&Bs_h[c << 3] = *(const u16x8*)&Bhi[gb];
      *(u16x8*)&Bs_l[c << 3] = *(const u16x8*)&Blo[gb];
    }
    __syncthreads();
    s16x8 ah[4], al[4], bh[4], bl[4];
    #pragma unroll
    for (int i = 0; i < 4; i++) {
      int ra = (wm * 64 + i * 16 + l16) * 32 + quad * 8;
      ah[i] = *(const s16x8*)&As_h[ra];
      al[i] = *(const s16x8*)&As_l[ra];
      int rb = (wn * 64 + i * 16 + l16) * 32 + quad * 8;
      bh[i] = *(const s16x8*)&Bs_h[rb];
      bl[i] = *(const s16x8*)&Bs_l[rb];
    }
    #pragma unroll
    for (int i = 0; i < 4; i++)
      #pragma unroll
      for (int j = 0; j < 4; j++) {
        acc[i][j] = __builtin_amdgcn_mfma_f32_16x16x32_bf16(ah[i], bl[j], acc[i][j], 0, 0, 0);
        acc[i][j] = __builtin_amdgcn_mfma_f32_16x16x32_bf16(al[i], bh[j], acc[i][j], 0, 0, 0);
        acc[i][j] = __builtin_amdgcn_mfma_f32_16x16x32_bf16(ah[i], bh[j], acc[i][j], 0, 0, 0);
      }
  }
  // epilogue: scatter with bias
  #pragma unroll
  for (int j = 0; j < 4; j++) {
    int n = n0 + wn * 64 + j * 16 + l16;
    float bv = bias[n];
    int which = n >> 10;                  // 0=Q 1=K 2=V
    int rem = n & 1023;
    int h = rem >> 6, d = rem & 63;
    #pragma unroll
    for (int i = 0; i < 4; i++)
      #pragma unroll
      for (int r = 0; r < 4; r++) {
        int m = m0 + wm * 64 + i * 16 + quad * 4 + r;
        int b = m >> 11, t = m & 2047;
        unsigned short u = f2bf(acc[i][j][r] + bv);
        int hb = b * NH + h;
        if (which == 0)      Qp[(size_t)hb * (SEQ * HD) + (size_t)t * HD + d] = u;
        else if (which == 1) Kp[(size_t)hb * (SEQ * HD) + (size_t)t * HD + d] = u;
        else                 Vt[(size_t)hb * (SEQ * HD) + (size_t)d * SEQ + t] = u;
      }
  }
}

// ---------------- kernel 4: flash attention ----------------------------------
// grid (qtile=32, bh=32), block 256 (4 waves); each wave: 16 q-rows
__global__ __launch_bounds__(256) void k_attn(const unsigned short* __restrict__ Qp,
                                              const unsigned short* __restrict__ Kp,
                                              const unsigned short* __restrict__ Vt,
                                              const float* __restrict__ mask,
                                              unsigned short* __restrict__ AO) {
  int tid = threadIdx.x, wave = tid >> 6, lane = tid & 63, quad = lane >> 4, l16 = lane & 15;
  int bh = blockIdx.y;
  int qbase = blockIdx.x * 64;
  const unsigned short* Qg = Qp + (size_t)bh * (SEQ * HD);
  const unsigned short* Kg = Kp + (size_t)bh * (SEQ * HD);
  const unsigned short* Vg = Vt + (size_t)bh * (SEQ * HD);   // [d][t]
  __shared__ __align__(16) unsigned short Qs[64 * 64], Ks[64 * 64], Vs[64 * 64];
  __shared__ __align__(16) unsigned short Ps[4][16 * 64];
  // stage Q tile [64 rows][64 d]
  for (int c = tid; c < 512; c += 256) {
    int row = c >> 3, co = (c & 7) << 3;
    *(u16x8*)&Qs[c << 3] = *(const u16x8*)&Qg[(size_t)(qbase + row) * HD + co];
  }
  float m_i[4], l_i[4];
  f32x4 acc_o[4] = {};
  #pragma unroll
  for (int r = 0; r < 4; r++) { m_i[r] = -3.0e38f; l_i[r] = 0.f; }
  int qrow = qbase + wave * 16 + quad * 4;      // this lane's first q row (t index)

  for (int kt = 0; kt < 32; kt++) {
    int kbase = kt * 64;
    __syncthreads();
    for (int c = tid; c < 512; c += 256) {
      int row = c >> 3, co = (c & 7) << 3;
      *(u16x8*)&Ks[c << 3] = *(const u16x8*)&Kg[(size_t)(kbase + row) * HD + co];
      *(u16x8*)&Vs[c << 3] = *(const u16x8*)&Vg[(size_t)row * SEQ + kbase + co];
    }
    __syncthreads();
    // S = Q K^T for this wave's 16 rows x 64 cols
    f32x4 s[4] = {};
    #pragma unroll
    for (int nt = 0; nt < 4; nt++)
      #pragma unroll
      for (int kk = 0; kk < 2; kk++) {
        s16x8 a = *(const s16x8*)&Qs[(wave * 16 + l16) * 64 + kk * 32 + quad * 8];
        s16x8 b = *(const s16x8*)&Ks[(nt * 16 + l16) * 64 + kk * 32 + quad * 8];
        s[nt] = __builtin_amdgcn_mfma_f32_16x16x32_bf16(a, b, s[nt], 0, 0, 0);
      }
    // scale + mask
    float sv[4][4];
    #pragma unroll
    for (int nt = 0; nt < 4; nt++) {
      int kc = kbase + nt * 16 + l16;
      #pragma unroll
      for (int r = 0; r < 4; r++) {
        float mk = mask[(size_t)(qrow + r) * SEQ + kc];
        sv[nt][r] = (mk == 0.f) ? -1e30f : s[nt][r] * 0.125f;
      }
    }
    // online softmax per row
    float alpha[4], mnew[4];
    #pragma unroll
    for (int r = 0; r < 4; r++) {
      float v = fmaxf(fmaxf(sv[0][r], sv[1][r]), fmaxf(sv[2][r], sv[3][r]));
      for (int off = 1; off < 16; off <<= 1) v = fmaxf(v, __shfl_xor(v, off, 64));
      mnew[r] = fmaxf(m_i[r], v);
      alpha[r] = __expf(m_i[r] - mnew[r]);
      m_i[r] = mnew[r];
    }
    #pragma unroll
    for (int r = 0; r < 4; r++) {
      float lsum = 0.f;
      #pragma unroll
      for (int nt = 0; nt < 4; nt++) {
        float p = __expf(sv[nt][r] - mnew[r]);
        lsum += p;
        Ps[wave][(quad * 4 + r) * 64 + nt * 16 + l16] = f2bf(p);
      }
      for (int off = 1; off < 16; off <<= 1) lsum += __shfl_xor(lsum, off, 64);
      l_i[r] = l_i[r] * alpha[r] + lsum;
      acc_o[0][r] *= alpha[r]; acc_o[1][r] *= alpha[r];
      acc_o[2][r] *= alpha[r]; acc_o[3][r] *= alpha[r];
    }
    // O += P @ V   (P from LDS in A-layout, V^T tile is B-operand layout)
    #pragma unroll
    for (int nt = 0; nt < 4; nt++)
      #pragma unroll
      for (int kk = 0; kk < 2; kk++) {
        s16x8 a = *(const s16x8*)&Ps[wave][l16 * 64 + kk * 32 + quad * 8];
        s16x8 b = *(const s16x8*)&Vs[(nt * 16 + l16) * 64 + kk * 32 + quad * 8];
        acc_o[nt] = __builtin_amdgcn_mfma_f32_16x16x32_bf16(a, b, acc_o[nt], 0, 0, 0);
      }
  }
  // epilogue: normalize, write bf16 attn-out [m][c]
  int b = bh >> 4, h = bh & 15;
  #pragma unroll
  for (int nt = 0; nt < 4; nt++)
    #pragma unroll
    for (int r = 0; r < 4; r++) {
      float o = acc_o[nt][r] / l_i[r];
      int m = b * SEQ + qrow + r;
      AO[(size_t)m * HID + h * HD + nt * 16 + l16] = f2bf(o);
    }
}

// ---------------- kernel 5: proj GEMM (single bf16) + bias -> fp32 -----------
__global__ __launch_bounds__(256) void k_gemm_proj(const unsigned short* __restrict__ A,
                                                   const unsigned short* __restrict__ Bt,
                                                   const float* __restrict__ bias,
                                                   float* __restrict__ out) {
  const int K = HID;
  int tid = threadIdx.x;
  int wave = tid >> 6, lane = tid & 63, quad = lane >> 4, l16 = lane & 15;
  int wm = wave >> 1, wn = wave & 1;
  int m0 = blockIdx.y * 128, n0 = blockIdx.x * 128;
  __shared__ __align__(16) unsigned short As[128 * 32], Bs[128 * 32];
  f32x4 acc[4][4] = {};
  for (int k0 = 0; k0 < K; k0 += 32) {
    __syncthreads();
    for (int c = tid; c < 512; c += 256) {
      int r = c >> 2, co = (c & 3) << 3;
      *(u16x8*)&As[c << 3] = *(const u16x8*)&A[(size_t)(m0 + r) * K + k0 + co];
      *(u16x8*)&Bs[c << 3] = *(const u16x8*)&Bt[(size_t)(n0 + r) * K + k0 + co];
    }
    __syncthreads();
    s16x8 af[4], bf[4];
    #pragma unroll
    for (int i = 0; i < 4; i++) {
      af[i] = *(const s16x8*)&As[(wm * 64 + i * 16 + l16) * 32 + quad * 8];
      bf[i] = *(const s16x8*)&Bs[(wn * 64 + i * 16 + l16) * 32 + quad * 8];
    }
    #pragma unroll
    for (int i = 0; i < 4; i++)
      #pragma unroll
      for (int j = 0; j < 4; j++)
        acc[i][j] = __builtin_amdgcn_mfma_f32_16x16x32_bf16(af[i], bf[j], acc[i][j], 0, 0, 0);
  }
  #pragma unroll
  for (int j = 0; j < 4; j++) {
    int n = n0 + wn * 64 + j * 16 + l16;
    float bv = bias[n];
    #pragma unroll
    for (int i = 0; i < 4; i++)
      #pragma unroll
      for (int r = 0; r < 4; r++) {
        int m = m0 + wm * 64 + i * 16 + quad * 4 + r;
        out[(size_t)m * HID + n] = acc[i][j][r] + bv;
      }
  }
}

// ---------------- launch -----------------------------------------------------
extern "C" void kernel_launch(void* const* d_in, const int* in_sizes, int n_in,
                              void* d_out, int out_size, void* d_ws, size_t ws_size,
                              hipStream_t stream) {
  const float* x     = (const float*)d_in[0];
  const float* mask  = (const float*)d_in[1];
  const float* Wqkv  = (const float*)d_in[2];
  const float* bqkv  = (const float*)d_in[3];
  const float* Wproj = (const float*)d_in[4];
  const float* bproj = (const float*)d_in[5];
  float* out = (float*)d_out;

  uint8_t* ws = (uint8_t*)d_ws;
  size_t off = 0;
  auto alloc = [&](size_t bytes) -> unsigned short* {
    unsigned short* p = (unsigned short*)(ws + off);
    off += (bytes + 255) & ~(size_t)255;
    return p;
  };
  unsigned short* xhi  = alloc((size_t)MR * HID * 2);
  unsigned short* xlo  = alloc((size_t)MR * HID * 2);
  unsigned short* WqT_h = alloc((size_t)NQKV * HID * 2);
  unsigned short* WqT_l = alloc((size_t)NQKV * HID * 2);
  unsigned short* WpT_h = alloc((size_t)HID * HID * 2);
  unsigned short* Qp   = alloc((size_t)BATCH * NH * SEQ * HD * 2);
  unsigned short* Kp   = alloc((size_t)BATCH * NH * SEQ * HD * 2);
  unsigned short* Vtp  = alloc((size_t)BATCH * NH * SEQ * HD * 2);
  unsigned short* AO   = alloc((size_t)MR * HID * 2);

  k_split_x<<<MR * HID / 4 / 256, 256, 0, stream>>>((const float4*)x, xhi, xlo);
  k_transpose_split<<<dim3(NQKV / 32, HID / 32), dim3(32, 8), 0, stream>>>(
      Wqkv, HID, NQKV, WqT_h, WqT_l);
  k_transpose_split<<<dim3(HID / 32, HID / 32), dim3(32, 8), 0, stream>>>(
      Wproj, HID, HID, WpT_h, nullptr);
  k_gemm_qkv<<<dim3(NQKV / 128, MR / 128), 256, 0, stream>>>(
      xhi, xlo, WqT_h, WqT_l, bqkv, Qp, Kp, Vtp);
  k_attn<<<dim3(SEQ / 64, BATCH * NH), 256, 0, stream>>>(Qp, Kp, Vtp, mask, AO);
  k_gemm_proj<<<dim3(HID / 128, MR / 128), 256, 0, stream>>>(AO, WpT_h, bproj, out);
}

// Round 3
// 288.031 us; speedup vs baseline: 1.3828x; 1.3828x over previous
//
#include <hip/hip_runtime.h>
#include <stdint.h>

#define HID 1024
#define NH 16
#define HD 64
#define BATCH 2
#define SEQ 2048
#define MR (BATCH*SEQ)        // 4096 token rows
#define NQKV (3*HID)          // 3072

typedef __attribute__((ext_vector_type(8))) _Float16 h16x8;
typedef __attribute__((ext_vector_type(8))) unsigned short u16x8;
typedef __attribute__((ext_vector_type(4))) float f32x4;

#if __has_builtin(__builtin_amdgcn_exp2f)
#define EXP2(x) __builtin_amdgcn_exp2f(x)
#else
#define EXP2(x) exp2f(x)
#endif

static __device__ __forceinline__ unsigned short f2h(float f) {
  union { _Float16 h; unsigned short u; } v; v.h = (_Float16)f; return v.u;
}

typedef const __attribute__((address_space(1))) unsigned int glb_u32;
typedef __attribute__((address_space(3))) unsigned int lds_u32;
static __device__ __forceinline__ void cp16(const void* g, void* l) {
  __builtin_amdgcn_global_load_lds((glb_u32*)g, (lds_u32*)l, 16, 0, 0);
}

// log2(e)/sqrt(HD): folded into Q so softmax runs in exp2 domain with no muls
#define QSCL (0.125f * 1.44269504f)

// ---------------- kernel 1: x fp32 -> fp16 -----------------------------------
__global__ __launch_bounds__(256) void k_cvt(const float4* __restrict__ src,
                                             ushort4* __restrict__ dst) {
  int i = blockIdx.x * 256 + threadIdx.x;
  float4 v = src[i];
  ushort4 h;
  h.x = f2h(v.x); h.y = f2h(v.y); h.z = f2h(v.z); h.w = f2h(v.w);
  dst[i] = h;
}

// -------- kernel 2: transpose fp32 [R][C] -> fp16 [C][R] ---------------------
__global__ __launch_bounds__(256) void k_transpose_h(const float* __restrict__ src,
                                                     int R, int C,
                                                     unsigned short* __restrict__ dst) {
  __shared__ float tile[32][33];
  int tx = threadIdx.x, ty = threadIdx.y;              // 32 x 8
  int col0 = blockIdx.x * 32, row0 = blockIdx.y * 32;
  #pragma unroll
  for (int i = 0; i < 32; i += 8)
    tile[ty + i][tx] = src[(size_t)(row0 + ty + i) * C + col0 + tx];
  __syncthreads();
  #pragma unroll
  for (int i = 0; i < 32; i += 8) {
    float v = tile[tx][ty + i];
    dst[(size_t)(col0 + ty + i) * R + row0 + tx] = f2h(v);
  }
}

// -------- kernel 3: mask -> bitmask (1 bit per element, u64 per 64 cols) -----
__global__ __launch_bounds__(256) void k_maskbits(const float* __restrict__ mask,
                                                  unsigned long long* __restrict__ mb) {
  int gw = blockIdx.x * 4 + (threadIdx.x >> 6);
  int lane = threadIdx.x & 63;
  float v = mask[(size_t)gw * 64 + lane];
  unsigned long long b = __ballot(v != 0.f);
  if (lane == 0) mb[gw] = b;
}

// ---------------- kernel 4: QKV GEMM (fp16, async staging) -------------------
// C[m][n] = A[m][k]*Bt[n][k] + bias[n]; scatter Q(pre-scaled),K,[V->Vt]
__global__ __launch_bounds__(256) void k_gemm_qkv(const unsigned short* __restrict__ A,
                                                  const unsigned short* __restrict__ Bt,
                                                  const float* __restrict__ bias,
                                                  unsigned short* __restrict__ Qp,
                                                  unsigned short* __restrict__ Kp,
                                                  unsigned short* __restrict__ Vt) {
  const int K = HID;
  int tid = threadIdx.x;
  int wave = tid >> 6, lane = tid & 63, quad = lane >> 4, l16 = lane & 15;
  int wm = wave >> 1, wn = wave & 1;
  int m0 = blockIdx.y * 128, n0 = blockIdx.x * 128;
  __shared__ __align__(16) unsigned short As[128 * 32], Bs[128 * 32];
  f32x4 acc[4][4] = {};
  for (int k0 = 0; k0 < K; k0 += 32) {
    __syncthreads();
    #pragma unroll
    for (int i = 0; i < 2; i++) {
      int c = tid + i * 256;
      int r = c >> 2, co = (c & 3) << 3;
      cp16(&A[(size_t)(m0 + r) * K + k0 + co], &As[c << 3]);
      cp16(&Bt[(size_t)(n0 + r) * K + k0 + co], &Bs[c << 3]);
    }
    __syncthreads();
    h16x8 af[4], bf[4];
    #pragma unroll
    for (int i = 0; i < 4; i++) {
      af[i] = *(const h16x8*)&As[(wm * 64 + i * 16 + l16) * 32 + quad * 8];
      bf[i] = *(const h16x8*)&Bs[(wn * 64 + i * 16 + l16) * 32 + quad * 8];
    }
    #pragma unroll
    for (int i = 0; i < 4; i++)
      #pragma unroll
      for (int j = 0; j < 4; j++)
        acc[i][j] = __builtin_amdgcn_mfma_f32_16x16x32_f16(af[i], bf[j], acc[i][j], 0, 0, 0);
  }
  #pragma unroll
  for (int j = 0; j < 4; j++) {
    int n = n0 + wn * 64 + j * 16 + l16;
    float bv = bias[n];
    int which = n >> 10;                  // 0=Q 1=K 2=V
    int rem = n & 1023;
    int h = rem >> 6, d = rem & 63;
    #pragma unroll
    for (int i = 0; i < 4; i++)
      #pragma unroll
      for (int r = 0; r < 4; r++) {
        int m = m0 + wm * 64 + i * 16 + quad * 4 + r;
        int b = m >> 11, t = m & 2047;
        float val = acc[i][j][r] + bv;
        int hb = b * NH + h;
        if (which == 0)      Qp[(size_t)hb * (SEQ * HD) + (size_t)t * HD + d] = f2h(val * QSCL);
        else if (which == 1) Kp[(size_t)hb * (SEQ * HD) + (size_t)t * HD + d] = f2h(val);
        else                 Vt[(size_t)hb * (SEQ * HD) + (size_t)d * SEQ + t] = f2h(val);
      }
  }
}

// ---------------- kernel 5: flash attention (S^T formulation) ----------------
// grid (qtile=32, bh=32), block 256 (4 waves, 16 q-rows each; q indexed by l16)
__global__ __launch_bounds__(256) void k_attn(const unsigned short* __restrict__ Qp,
                                              const unsigned short* __restrict__ Kp,
                                              const unsigned short* __restrict__ Vt,
                                              const unsigned long long* __restrict__ mb,
                                              unsigned short* __restrict__ AO) {
  int tid = threadIdx.x, wave = tid >> 6, lane = tid & 63, quad = lane >> 4, l16 = lane & 15;
  int bh = blockIdx.y, qbase = blockIdx.x * 64;
  const unsigned short* Qg = Qp + (size_t)bh * (SEQ * HD);
  const unsigned short* Kg = Kp + (size_t)bh * (SEQ * HD);
  const unsigned short* Vg = Vt + (size_t)bh * (SEQ * HD);   // [d][t]
  __shared__ __align__(16) unsigned short smem[16896];
  unsigned short* Qs = smem;                       // 64x64
  unsigned short* Ks = smem + 4096;                // 64x64
  unsigned short* Vs = smem + 8192;                // 64x64  [d][t]
  unsigned short* Ps = smem + 12288 + wave * (16 * 72);  // per-wave 16x72
  unsigned short* Os = smem + 4096;                // epilogue alias over Ks/Vs, 64x72

  #pragma unroll
  for (int i = 0; i < 2; i++) {
    int c = tid + i * 256;
    cp16(&Qg[(size_t)(qbase + (c >> 3)) * HD + ((c & 7) << 3)], &Qs[c << 3]);
  }
  int qrow = qbase + wave * 16 + l16;              // this lane's q row
  const unsigned long long* mrow = mb + (size_t)qrow * 32;
  float m_i = -3.0e38f, l_i = 0.f;
  f32x4 acc_o[4] = {};

  for (int kt = 0; kt < 32; kt++) {
    int kbase = kt * 64;
    __syncthreads();
    #pragma unroll
    for (int i = 0; i < 2; i++) {
      int c = tid + i * 256;
      int row = c >> 3, co = (c & 7) << 3;
      cp16(&Kg[(size_t)(kbase + row) * HD + co], &Ks[c << 3]);
      cp16(&Vg[(size_t)row * SEQ + kbase + co], &Vs[c << 3]);
    }
    unsigned long long w = mrow[kt];
    __syncthreads();
    // S^T: lane holds S[q=l16][k=nt*16+quad*4+r]  (log2 domain, Q pre-scaled)
    f32x4 s[4] = {};
    h16x8 bq[2];
    #pragma unroll
    for (int kk = 0; kk < 2; kk++)
      bq[kk] = *(const h16x8*)&Qs[(wave * 16 + l16) * 64 + kk * 32 + quad * 8];
    #pragma unroll
    for (int nt = 0; nt < 4; nt++)
      #pragma unroll
      for (int kk = 0; kk < 2; kk++) {
        h16x8 a = *(const h16x8*)&Ks[(nt * 16 + l16) * 64 + kk * 32 + quad * 8];
        s[nt] = __builtin_amdgcn_mfma_f32_16x16x32_f16(a, bq[kk], s[nt], 0, 0, 0);
      }
    if (!__all(w == ~0ULL)) {                      // wave-uniform fast path
      #pragma unroll
      for (int nt = 0; nt < 4; nt++)
        #pragma unroll
        for (int r = 0; r < 4; r++)
          if (!((w >> (nt * 16 + quad * 4 + r)) & 1ULL)) s[nt][r] = -1e30f;
    }
    // per-q max: 15 in-register + cross-quad (quads are the k-partitions)
    float v = s[0][0];
    #pragma unroll
    for (int nt = 0; nt < 4; nt++)
      #pragma unroll
      for (int r = 0; r < 4; r++) v = fmaxf(v, s[nt][r]);
    v = fmaxf(v, __shfl_xor(v, 16));
    v = fmaxf(v, __shfl_xor(v, 32));
    float mnew = fmaxf(m_i, v);
    float alpha = EXP2(m_i - mnew);
    m_i = mnew;
    float lsum = 0.f;
    #pragma unroll
    for (int nt = 0; nt < 4; nt++)
      #pragma unroll
      for (int r = 0; r < 4; r++) {
        s[nt][r] = EXP2(s[nt][r] - mnew);          // p, in place
        lsum += s[nt][r];
      }
    lsum += __shfl_xor(lsum, 16);
    lsum += __shfl_xor(lsum, 32);
    l_i = l_i * alpha + lsum;
    #pragma unroll
    for (int nt = 0; nt < 4; nt++)
      #pragma unroll
      for (int r = 0; r < 4; r++) acc_o[nt][r] *= alpha;
    // P -> LDS, packed b64 (lane owns 4 consecutive k per nt)
    #pragma unroll
    for (int nt = 0; nt < 4; nt++) {
      uint2 t;
      t.x = (unsigned)f2h(s[nt][0]) | ((unsigned)f2h(s[nt][1]) << 16);
      t.y = (unsigned)f2h(s[nt][2]) | ((unsigned)f2h(s[nt][3]) << 16);
      *(uint2*)&Ps[l16 * 72 + nt * 16 + quad * 4] = t;
    }
    h16x8 bp[2];
    #pragma unroll
    for (int kk = 0; kk < 2; kk++)
      bp[kk] = *(const h16x8*)&Ps[l16 * 72 + kk * 32 + quad * 8];
    // O^T += V^T P : acc_o[nt] row = d = nt*16+quad*4+r, col = q = l16
    #pragma unroll
    for (int nt = 0; nt < 4; nt++)
      #pragma unroll
      for (int kk = 0; kk < 2; kk++) {
        h16x8 a = *(const h16x8*)&Vs[(nt * 16 + l16) * 64 + kk * 32 + quad * 8];
        acc_o[nt] = __builtin_amdgcn_mfma_f32_16x16x32_f16(a, bp[kk], acc_o[nt], 0, 0, 0);
      }
  }
  // epilogue: normalize (per-lane scalar), transpose via LDS, coalesced store
  float rl = 1.0f / l_i;
  __syncthreads();
  #pragma unroll
  for (int nt = 0; nt < 4; nt++) {
    uint2 t;
    t.x = (unsigned)f2h(acc_o[nt][0] * rl) | ((unsigned)f2h(acc_o[nt][1] * rl) << 16);
    t.y = (unsigned)f2h(acc_o[nt][2] * rl) | ((unsigned)f2h(acc_o[nt][3] * rl) << 16);
    // BUGFIX (R2): row is this wave's q row (wave*16 + l16), not l16 alone —
    // all 4 waves were stomping rows 0..15 of the shared Os tile.
    *(uint2*)&Os[(wave * 16 + l16) * 72 + nt * 16 + quad * 4] = t;
  }
  __syncthreads();
  int b = bh >> 4, h = bh & 15;
  #pragma unroll
  for (int i = 0; i < 2; i++) {
    int c = tid + i * 256;
    int row = c >> 3, co = (c & 7) << 3;
    u16x8 vv = *(const u16x8*)&Os[row * 72 + co];
    *(u16x8*)&AO[(size_t)(b * SEQ + qbase + row) * HID + h * HD + co] = vv;
  }
}

// ---------------- kernel 6: proj GEMM (fp16) + bias -> fp32 ------------------
__global__ __launch_bounds__(256) void k_gemm_proj(const unsigned short* __restrict__ A,
                                                   const unsigned short* __restrict__ Bt,
                                                   const float* __restrict__ bias,
                                                   float* __restrict__ out) {
  const int K = HID;
  int tid = threadIdx.x;
  int wave = tid >> 6, lane = tid & 63, quad = lane >> 4, l16 = lane & 15;
  int wm = wave >> 1, wn = wave & 1;
  int m0 = blockIdx.y * 128, n0 = blockIdx.x * 128;
  __shared__ __align__(16) unsigned short As[128 * 32], Bs[128 * 32];
  f32x4 acc[4][4] = {};
  for (int k0 = 0; k0 < K; k0 += 32) {
    __syncthreads();
    #pragma unroll
    for (int i = 0; i < 2; i++) {
      int c = tid + i * 256;
      int r = c >> 2, co = (c & 3) << 3;
      cp16(&A[(size_t)(m0 + r) * K + k0 + co], &As[c << 3]);
      cp16(&Bt[(size_t)(n0 + r) * K + k0 + co], &Bs[c << 3]);
    }
    __syncthreads();
    h16x8 af[4], bf[4];
    #pragma unroll
    for (int i = 0; i < 4; i++) {
      af[i] = *(const h16x8*)&As[(wm * 64 + i * 16 + l16) * 32 + quad * 8];
      bf[i] = *(const h16x8*)&Bs[(wn * 64 + i * 16 + l16) * 32 + quad * 8];
    }
    #pragma unroll
    for (int i = 0; i < 4; i++)
      #pragma unroll
      for (int j = 0; j < 4; j++)
        acc[i][j] = __builtin_amdgcn_mfma_f32_16x16x32_f16(af[i], bf[j], acc[i][j], 0, 0, 0);
  }
  #pragma unroll
  for (int j = 0; j < 4; j++) {
    int n = n0 + wn * 64 + j * 16 + l16;
    float bv = bias[n];
    #pragma unroll
    for (int i = 0; i < 4; i++)
      #pragma unroll
      for (int r = 0; r < 4; r++) {
        int m = m0 + wm * 64 + i * 16 + quad * 4 + r;
        out[(size_t)m * HID + n] = acc[i][j][r] + bv;
      }
  }
}

// ---------------- launch -----------------------------------------------------
extern "C" void kernel_launch(void* const* d_in, const int* in_sizes, int n_in,
                              void* d_out, int out_size, void* d_ws, size_t ws_size,
                              hipStream_t stream) {
  const float* x     = (const float*)d_in[0];
  const float* mask  = (const float*)d_in[1];
  const float* Wqkv  = (const float*)d_in[2];
  const float* bqkv  = (const float*)d_in[3];
  const float* Wproj = (const float*)d_in[4];
  const float* bproj = (const float*)d_in[5];
  float* out = (float*)d_out;

  uint8_t* ws = (uint8_t*)d_ws;
  size_t off = 0;
  auto alloc = [&](size_t bytes) -> void* {
    void* p = (void*)(ws + off);
    off += (bytes + 255) & ~(size_t)255;
    return p;
  };
  unsigned short* xh   = (unsigned short*)alloc((size_t)MR * HID * 2);
  unsigned short* WqT  = (unsigned short*)alloc((size_t)NQKV * HID * 2);
  unsigned short* WpT  = (unsigned short*)alloc((size_t)HID * HID * 2);
  unsigned short* Qp   = (unsigned short*)alloc((size_t)BATCH * NH * SEQ * HD * 2);
  unsigned short* Kp   = (unsigned short*)alloc((size_t)BATCH * NH * SEQ * HD * 2);
  unsigned short* Vtp  = (unsigned short*)alloc((size_t)BATCH * NH * SEQ * HD * 2);
  unsigned short* AO   = (unsigned short*)alloc((size_t)MR * HID * 2);
  unsigned long long* mb = (unsigned long long*)alloc((size_t)SEQ * (SEQ / 64) * 8);

  k_cvt<<<MR * HID / 4 / 256, 256, 0, stream>>>((const float4*)x, (ushort4*)xh);
  k_transpose_h<<<dim3(NQKV / 32, HID / 32), dim3(32, 8), 0, stream>>>(Wqkv, HID, NQKV, WqT);
  k_transpose_h<<<dim3(HID / 32, HID / 32), dim3(32, 8), 0, stream>>>(Wproj, HID, HID, WpT);
  k_maskbits<<<SEQ * (SEQ / 64) / 4, 256, 0, stream>>>(mask, mb);
  k_gemm_qkv<<<dim3(NQKV / 128, MR / 128), 256, 0, stream>>>(xh, WqT, bqkv, Qp, Kp, Vtp);
  k_attn<<<dim3(SEQ / 64, BATCH * NH), 256, 0, stream>>>(Qp, Kp, Vtp, mb, AO);
  k_gemm_proj<<<dim3(HID / 128, MR / 128), 256, 0, stream>>>(AO, WpT, bproj, out);
}

// Round 5
// 234.551 us; speedup vs baseline: 1.6981x; 1.2280x over previous
//
#include <hip/hip_runtime.h>
#include <stdint.h>

#define HID 1024
#define NH 16
#define HD 64
#define BATCH 2
#define SEQ 2048
#define MR (BATCH*SEQ)        // 4096 token rows
#define NQKV (3*HID)          // 3072

typedef __attribute__((ext_vector_type(8))) _Float16 h16x8;
typedef __attribute__((ext_vector_type(2))) __fp16 fp16x2;
typedef __attribute__((ext_vector_type(8))) unsigned short u16x8;
typedef __attribute__((ext_vector_type(4))) float f32x4;

#if __has_builtin(__builtin_amdgcn_exp2f)
#define EXP2(x) __builtin_amdgcn_exp2f(x)
#else
#define EXP2(x) exp2f(x)
#endif

static __device__ __forceinline__ unsigned short f2h(float f) {
  union { _Float16 h; unsigned short u; } v; v.h = (_Float16)f; return v.u;
}
// packed f32x2 -> f16x2 (RTZ), 1 instr
static __device__ __forceinline__ unsigned pk2(float a, float b) {
  union { fp16x2 h; unsigned u; } v;
  v.h = __builtin_amdgcn_cvt_pkrtz(a, b);
  return v.u;
}

typedef const __attribute__((address_space(1))) unsigned int glb_u32;
typedef __attribute__((address_space(3))) unsigned int lds_u32;
static __device__ __forceinline__ void cp16(const void* g, void* l) {
  __builtin_amdgcn_global_load_lds((glb_u32*)g, (lds_u32*)l, 16, 0, 0);
}

// log2(e)/sqrt(HD): folded into Q so softmax runs in exp2 domain with no muls
#define QSCL (0.125f * 1.44269504f)

// ---------------- kernel 1: x fp32 -> fp16 -----------------------------------
__global__ __launch_bounds__(256) void k_cvt(const float4* __restrict__ src,
                                             ushort4* __restrict__ dst) {
  int i = blockIdx.x * 256 + threadIdx.x;
  float4 v = src[i];
  ushort4 h;
  h.x = f2h(v.x); h.y = f2h(v.y); h.z = f2h(v.z); h.w = f2h(v.w);
  dst[i] = h;
}

// -------- kernel 2: transpose fp32 [R][C] -> fp16 [C][R] ---------------------
__global__ __launch_bounds__(256) void k_transpose_h(const float* __restrict__ src,
                                                     int R, int C,
                                                     unsigned short* __restrict__ dst) {
  __shared__ float tile[32][33];
  int tx = threadIdx.x, ty = threadIdx.y;              // 32 x 8
  int col0 = blockIdx.x * 32, row0 = blockIdx.y * 32;
  #pragma unroll
  for (int i = 0; i < 32; i += 8)
    tile[ty + i][tx] = src[(size_t)(row0 + ty + i) * C + col0 + tx];
  __syncthreads();
  #pragma unroll
  for (int i = 0; i < 32; i += 8) {
    float v = tile[tx][ty + i];
    dst[(size_t)(col0 + ty + i) * R + row0 + tx] = f2h(v);
  }
}

// -------- kernel 3: mask -> bitmask (1 bit per element, u64 per 64 cols) -----
__global__ __launch_bounds__(256) void k_maskbits(const float* __restrict__ mask,
                                                  unsigned long long* __restrict__ mb) {
  int gw = blockIdx.x * 4 + (threadIdx.x >> 6);
  int lane = threadIdx.x & 63;
  float v = mask[(size_t)gw * 64 + lane];
  unsigned long long b = __ballot(v != 0.f);
  if (lane == 0) mb[gw] = b;
}

// ---------------- kernel 4: QKV GEMM (fp16, async staging) -------------------
// C[m][n] = A[m][k]*Bt[n][k] + bias[n]; scatter Q(pre-scaled),K,[V->Vt]
__global__ __launch_bounds__(256) void k_gemm_qkv(const unsigned short* __restrict__ A,
                                                  const unsigned short* __restrict__ Bt,
                                                  const float* __restrict__ bias,
                                                  unsigned short* __restrict__ Qp,
                                                  unsigned short* __restrict__ Kp,
                                                  unsigned short* __restrict__ Vt) {
  const int K = HID;
  int tid = threadIdx.x;
  int wave = tid >> 6, lane = tid & 63, quad = lane >> 4, l16 = lane & 15;
  int wm = wave >> 1, wn = wave & 1;
  int m0 = blockIdx.y * 128, n0 = blockIdx.x * 128;
  __shared__ __align__(16) unsigned short As[128 * 32], Bs[128 * 32];
  f32x4 acc[4][4] = {};
  for (int k0 = 0; k0 < K; k0 += 32) {
    __syncthreads();
    #pragma unroll
    for (int i = 0; i < 2; i++) {
      int c = tid + i * 256;
      int r = c >> 2, co = (c & 3) << 3;
      cp16(&A[(size_t)(m0 + r) * K + k0 + co], &As[c << 3]);
      cp16(&Bt[(size_t)(n0 + r) * K + k0 + co], &Bs[c << 3]);
    }
    __syncthreads();
    h16x8 af[4], bf[4];
    #pragma unroll
    for (int i = 0; i < 4; i++) {
      af[i] = *(const h16x8*)&As[(wm * 64 + i * 16 + l16) * 32 + quad * 8];
      bf[i] = *(const h16x8*)&Bs[(wn * 64 + i * 16 + l16) * 32 + quad * 8];
    }
    #pragma unroll
    for (int i = 0; i < 4; i++)
      #pragma unroll
      for (int j = 0; j < 4; j++)
        acc[i][j] = __builtin_amdgcn_mfma_f32_16x16x32_f16(af[i], bf[j], acc[i][j], 0, 0, 0);
  }
  #pragma unroll
  for (int j = 0; j < 4; j++) {
    int n = n0 + wn * 64 + j * 16 + l16;
    float bv = bias[n];
    int which = n >> 10;                  // 0=Q 1=K 2=V  (uniform per block)
    int rem = n & 1023;
    int h = rem >> 6, d = rem & 63;
    if (which == 2) {
      // V: r=0..3 are consecutive t in Vt[d][t] -> one 8B packed store per i
      #pragma unroll
      for (int i = 0; i < 4; i++) {
        int m = m0 + wm * 64 + i * 16 + quad * 4;
        int b = m >> 11, t = m & 2047;
        uint2 tt;
        tt.x = pk2(acc[i][j][0] + bv, acc[i][j][1] + bv);
        tt.y = pk2(acc[i][j][2] + bv, acc[i][j][3] + bv);
        *(uint2*)&Vt[(size_t)(b * NH + h) * (SEQ * HD) + (size_t)d * SEQ + t] = tt;
      }
    } else {
      #pragma unroll
      for (int i = 0; i < 4; i++)
        #pragma unroll
        for (int r = 0; r < 4; r++) {
          int m = m0 + wm * 64 + i * 16 + quad * 4 + r;
          int b = m >> 11, t = m & 2047;
          float val = acc[i][j][r] + bv;
          int hb = b * NH + h;
          if (which == 0) Qp[(size_t)hb * (SEQ * HD) + (size_t)t * HD + d] = f2h(val * QSCL);
          else            Kp[(size_t)hb * (SEQ * HD) + (size_t)t * HD + d] = f2h(val);
        }
    }
  }
}

// ---------------- kernel 5: flash attention (S^T formulation) ----------------
// grid (qtile=32, bh=32), block 256 (4 waves, 16 q-rows each; q indexed by l16)
// LDS tiles XOR-swizzled: 16B chunk c of row r stored at chunk c^(r&7).
// (global_load_lds requires packed dest; swizzle is applied on the per-lane
//  SOURCE address, readers xor the chunk index -> all-32-bank, 2-way = free)
__global__ __launch_bounds__(256) void k_attn(const unsigned short* __restrict__ Qp,
                                              const unsigned short* __restrict__ Kp,
                                              const unsigned short* __restrict__ Vt,
                                              const unsigned long long* __restrict__ mb,
                                              unsigned short* __restrict__ AO) {
  int tid = threadIdx.x, wave = tid >> 6, lane = tid & 63, quad = lane >> 4, l16 = lane & 15;
  int bh = blockIdx.y, qbase = blockIdx.x * 64;
  const unsigned short* Qg = Qp + (size_t)bh * (SEQ * HD);
  const unsigned short* Kg = Kp + (size_t)bh * (SEQ * HD);
  const unsigned short* Vg = Vt + (size_t)bh * (SEQ * HD);   // [d][t]
  __shared__ __align__(16) unsigned short smem[16896];
  unsigned short* Qs = smem;                       // 64x64 swizzled
  unsigned short* Ks = smem + 4096;                // 64x64 swizzled
  unsigned short* Vs = smem + 8192;                // 64x64 swizzled [d][t]
  unsigned short* Ps = smem + 12288 + wave * (16 * 72);  // per-wave 16x72
  unsigned short* Os = smem + 4096;                // epilogue alias over Ks/Vs, 64x72

  #pragma unroll
  for (int i = 0; i < 2; i++) {
    int c = tid + i * 256;
    int row = c >> 3, sc = ((c ^ row) & 7) << 3;
    cp16(&Qg[(size_t)(qbase + row) * HD + sc], &Qs[c << 3]);
  }
  int qrow = qbase + wave * 16 + l16;              // this lane's q row
  const unsigned long long* mrow = mb + (size_t)qrow * 32;
  float m_i = -3.0e38f, l_i = 0.f;
  f32x4 acc_o[4] = {};
  int x7 = l16 & 7;                                // row&7 for all frag reads

  for (int kt = 0; kt < 32; kt++) {
    int kbase = kt * 64;
    __syncthreads();
    #pragma unroll
    for (int i = 0; i < 2; i++) {
      int c = tid + i * 256;
      int row = c >> 3, sc = ((c ^ row) & 7) << 3;
      cp16(&Kg[(size_t)(kbase + row) * HD + sc], &Ks[c << 3]);
      cp16(&Vg[(size_t)row * SEQ + kbase + sc], &Vs[c << 3]);
    }
    unsigned long long w = mrow[kt];
    __syncthreads();
    // S^T: lane holds S[q=l16][k=nt*16+quad*4+r]  (log2 domain, Q pre-scaled)
    f32x4 s[4] = {};
    h16x8 bq[2];
    #pragma unroll
    for (int kk = 0; kk < 2; kk++)
      bq[kk] = *(const h16x8*)&Qs[(wave * 16 + l16) * 64 + (((kk * 4 + quad) ^ x7) << 3)];
    #pragma unroll
    for (int nt = 0; nt < 4; nt++)
      #pragma unroll
      for (int kk = 0; kk < 2; kk++) {
        h16x8 a = *(const h16x8*)&Ks[(nt * 16 + l16) * 64 + (((kk * 4 + quad) ^ x7) << 3)];
        s[nt] = __builtin_amdgcn_mfma_f32_16x16x32_f16(a, bq[kk], s[nt], 0, 0, 0);
      }
    if (!__all(w == ~0ULL)) {                      // wave-uniform fast path
      #pragma unroll
      for (int nt = 0; nt < 4; nt++)
        #pragma unroll
        for (int r = 0; r < 4; r++)
          if (!((w >> (nt * 16 + quad * 4 + r)) & 1ULL)) s[nt][r] = -1e30f;
    }
    // per-q max: 15 in-register + cross-quad (quads are the k-partitions)
    float v = s[0][0];
    #pragma unroll
    for (int nt = 0; nt < 4; nt++)
      #pragma unroll
      for (int r = 0; r < 4; r++) v = fmaxf(v, s[nt][r]);
    v = fmaxf(v, __shfl_xor(v, 16));
    v = fmaxf(v, __shfl_xor(v, 32));
    float mnew = fmaxf(m_i, v);
    float alpha = EXP2(m_i - mnew);
    m_i = mnew;
    float lsum = 0.f;
    #pragma unroll
    for (int nt = 0; nt < 4; nt++)
      #pragma unroll
      for (int r = 0; r < 4; r++) {
        s[nt][r] = EXP2(s[nt][r] - mnew);          // p, in place
        lsum += s[nt][r];
      }
    lsum += __shfl_xor(lsum, 16);
    lsum += __shfl_xor(lsum, 32);
    l_i = l_i * alpha + lsum;
    #pragma unroll
    for (int nt = 0; nt < 4; nt++)
      #pragma unroll
      for (int r = 0; r < 4; r++) acc_o[nt][r] *= alpha;
    // P -> LDS, packed b64 via v_cvt_pkrtz (lane owns 4 consecutive k per nt)
    #pragma unroll
    for (int nt = 0; nt < 4; nt++) {
      uint2 t;
      t.x = pk2(s[nt][0], s[nt][1]);
      t.y = pk2(s[nt][2], s[nt][3]);
      *(uint2*)&Ps[l16 * 72 + nt * 16 + quad * 4] = t;
    }
    h16x8 bp[2];
    #pragma unroll
    for (int kk = 0; kk < 2; kk++)
      bp[kk] = *(const h16x8*)&Ps[l16 * 72 + kk * 32 + quad * 8];
    // O^T += V^T P : acc_o[nt] row = d = nt*16+quad*4+r, col = q = l16
    #pragma unroll
    for (int nt = 0; nt < 4; nt++)
      #pragma unroll
      for (int kk = 0; kk < 2; kk++) {
        h16x8 a = *(const h16x8*)&Vs[(nt * 16 + l16) * 64 + (((kk * 4 + quad) ^ x7) << 3)];
        acc_o[nt] = __builtin_amdgcn_mfma_f32_16x16x32_f16(a, bp[kk], acc_o[nt], 0, 0, 0);
      }
  }
  // epilogue: normalize (per-lane scalar), transpose via LDS, coalesced store
  float rl = 1.0f / l_i;
  __syncthreads();
  #pragma unroll
  for (int nt = 0; nt < 4; nt++) {
    uint2 t;
    t.x = (unsigned)f2h(acc_o[nt][0] * rl) | ((unsigned)f2h(acc_o[nt][1] * rl) << 16);
    t.y = (unsigned)f2h(acc_o[nt][2] * rl) | ((unsigned)f2h(acc_o[nt][3] * rl) << 16);
    *(uint2*)&Os[(wave * 16 + l16) * 72 + nt * 16 + quad * 4] = t;
  }
  __syncthreads();
  int b = bh >> 4, h = bh & 15;
  #pragma unroll
  for (int i = 0; i < 2; i++) {
    int c = tid + i * 256;
    int row = c >> 3, co = (c & 7) << 3;
    u16x8 vv = *(const u16x8*)&Os[row * 72 + co];
    *(u16x8*)&AO[(size_t)(b * SEQ + qbase + row) * HID + h * HD + co] = vv;
  }
}

// ---------------- kernel 6: proj GEMM (fp16) + bias -> fp32 ------------------
__global__ __launch_bounds__(256) void k_gemm_proj(const unsigned short* __restrict__ A,
                                                   const unsigned short* __restrict__ Bt,
                                                   const float* __restrict__ bias,
                                                   float* __restrict__ out) {
  const int K = HID;
  int tid = threadIdx.x;
  int wave = tid >> 6, lane = tid & 63, quad = lane >> 4, l16 = lane & 15;
  int wm = wave >> 1, wn = wave & 1;
  int m0 = blockIdx.y * 128, n0 = blockIdx.x * 128;
  __shared__ __align__(16) unsigned short As[128 * 32], Bs[128 * 32];
  f32x4 acc[4][4] = {};
  for (int k0 = 0; k0 < K; k0 += 32) {
    __syncthreads();
    #pragma unroll
    for (int i = 0; i < 2; i++) {
      int c = tid + i * 256;
      int r = c >> 2, co = (c & 3) << 3;
      cp16(&A[(size_t)(m0 + r) * K + k0 + co], &As[c << 3]);
      cp16(&Bt[(size_t)(n0 + r) * K + k0 + co], &Bs[c << 3]);
    }
    __syncthreads();
    h16x8 af[4], bf[4];
    #pragma unroll
    for (int i = 0; i < 4; i++) {
      af[i] = *(const h16x8*)&As[(wm * 64 + i * 16 + l16) * 32 + quad * 8];
      bf[i] = *(const h16x8*)&Bs[(wn * 64 + i * 16 + l16) * 32 + quad * 8];
    }
    #pragma unroll
    for (int i = 0; i < 4; i++)
      #pragma unroll
      for (int j = 0; j < 4; j++)
        acc[i][j] = __builtin_amdgcn_mfma_f32_16x16x32_f16(af[i], bf[j], acc[i][j], 0, 0, 0);
  }
  #pragma unroll
  for (int j = 0; j < 4; j++) {
    int n = n0 + wn * 64 + j * 16 + l16;
    float bv = bias[n];
    #pragma unroll
    for (int i = 0; i < 4; i++)
      #pragma unroll
      for (int r = 0; r < 4; r++) {
        int m = m0 + wm * 64 + i * 16 + quad * 4 + r;
        out[(size_t)m * HID + n] = acc[i][j][r] + bv;
      }
  }
}

// ---------------- launch -----------------------------------------------------
extern "C" void kernel_launch(void* const* d_in, const int* in_sizes, int n_in,
                              void* d_out, int out_size, void* d_ws, size_t ws_size,
                              hipStream_t stream) {
  const float* x     = (const float*)d_in[0];
  const float* mask  = (const float*)d_in[1];
  const float* Wqkv  = (const float*)d_in[2];
  const float* bqkv  = (const float*)d_in[3];
  const float* Wproj = (const float*)d_in[4];
  const float* bproj = (const float*)d_in[5];
  float* out = (float*)d_out;

  uint8_t* ws = (uint8_t*)d_ws;
  size_t off = 0;
  auto alloc = [&](size_t bytes) -> void* {
    void* p = (void*)(ws + off);
    off += (bytes + 255) & ~(size_t)255;
    return p;
  };
  unsigned short* xh   = (unsigned short*)alloc((size_t)MR * HID * 2);
  unsigned short* WqT  = (unsigned short*)alloc((size_t)NQKV * HID * 2);
  unsigned short* WpT  = (unsigned short*)alloc((size_t)HID * HID * 2);
  unsigned short* Qp   = (unsigned short*)alloc((size_t)BATCH * NH * SEQ * HD * 2);
  unsigned short* Kp   = (unsigned short*)alloc((size_t)BATCH * NH * SEQ * HD * 2);
  unsigned short* Vtp  = (unsigned short*)alloc((size_t)BATCH * NH * SEQ * HD * 2);
  unsigned short* AO   = (unsigned short*)alloc((size_t)MR * HID * 2);
  unsigned long long* mb = (unsigned long long*)alloc((size_t)SEQ * (SEQ / 64) * 8);

  k_cvt<<<MR * HID / 4 / 256, 256, 0, stream>>>((const float4*)x, (ushort4*)xh);
  k_transpose_h<<<dim3(NQKV / 32, HID / 32), dim3(32, 8), 0, stream>>>(Wqkv, HID, NQKV, WqT);
  k_transpose_h<<<dim3(HID / 32, HID / 32), dim3(32, 8), 0, stream>>>(Wproj, HID, HID, WpT);
  k_maskbits<<<SEQ * (SEQ / 64) / 4, 256, 0, stream>>>(mask, mb);
  k_gemm_qkv<<<dim3(NQKV / 128, MR / 128), 256, 0, stream>>>(xh, WqT, bqkv, Qp, Kp, Vtp);
  k_attn<<<dim3(SEQ / 64, BATCH * NH), 256, 0, stream>>>(Qp, Kp, Vtp, mb, AO);
  k_gemm_proj<<<dim3(HID / 128, MR / 128), 256, 0, stream>>>(AO, WpT, bproj, out);
}